// Round 7
// baseline (190.002 us; speedup 1.0000x reference)
//
#include <hip/hip_runtime.h>
#include <hip/hip_bf16.h>
#include <stdint.h>

typedef __attribute__((ext_vector_type(8))) __bf16 bf16x8;
typedef __attribute__((ext_vector_type(8))) unsigned short ushort8_t;
typedef __attribute__((ext_vector_type(4))) unsigned short ushort4_t;
typedef __attribute__((ext_vector_type(4))) float f32x4;

#define MFMA16(a, b, c) __builtin_amdgcn_mfma_f32_16x16x32_bf16((a), (b), (c), 0, 0, 0)

static __device__ __forceinline__ unsigned short f2bf(float f) {
  union { float f; unsigned u; } v; v.f = f;
  unsigned r = v.u + 0x7fffu + ((v.u >> 16) & 1u);  // RNE
  return (unsigned short)(r >> 16);
}
static __device__ __forceinline__ float bf2f(unsigned short u) {
  union { unsigned u; float f; } v; v.u = ((unsigned)u) << 16; return v.f;
}

static __device__ __forceinline__ void gld_lds16(const void* g, void* l) {
  __builtin_amdgcn_global_load_lds((const __attribute__((address_space(1))) void*)g,
                                   (__attribute__((address_space(3))) void*)l, 16, 0, 0);
}

// ---------------- kernel 0a: convert x f32 -> bf16 (row-major [65536][256])
__global__ __launch_bounds__(256) void k_convx(const float* __restrict__ x,
                                               unsigned short* __restrict__ xb) {
  size_t i = ((size_t)blockIdx.x * 256 + threadIdx.x) * 4;  // 16384 blocks exact
  float4 v = *(const float4*)(x + i);
  ushort4_t o = { f2bf(v.x), f2bf(v.y), f2bf(v.z), f2bf(v.w) };
  *(ushort4_t*)(xb + i) = o;
}

// ---------------- kernel 0b: convert w_qkv f32 -> bf16 ([1536][256])
__global__ void k_convw(const float* __restrict__ w, unsigned short* __restrict__ wb) {
  int i = (blockIdx.x * 256 + threadIdx.x) * 4;  // 384 blocks
  float4 v = *(const float4*)(w + i);
  ushort4_t o = { f2bf(v.x), f2bf(v.y), f2bf(v.z), f2bf(v.w) };
  *(ushort4_t*)(wb + i) = o;
}

// ---------------- kernel 0c: convert w_out f32 -> bf16 ([256][512])
__global__ void k_convo(const float* __restrict__ w, unsigned short* __restrict__ wb) {
  int i = (blockIdx.x * 256 + threadIdx.x) * 4;  // 128 blocks
  float4 v = *(const float4*)(w + i);
  ushort4_t o = { f2bf(v.x), f2bf(v.y), f2bf(v.z), f2bf(v.w) };
  *(ushort4_t*)(wb + i) = o;
}

// ---------------- kernel 1: FUSED K/V projection + instance-norm + dots, 4-phase GEMM core.
// Block = 2 heads (hp, hp+4), loops G=4 m-tiles of 256 rows. Output tile 256x256 =
// [K_h|V_h|K_h2|V_h2]; norms rows in-register; LDS-transpose overlay; dots acc in regs.
__global__ __launch_bounds__(512) void k_fused(const unsigned short* __restrict__ xb,
                                               const unsigned short* __restrict__ wqb,
                                               float* __restrict__ partials) {
  __shared__ __align__(16) char smem[147456];            // 144 KB
  unsigned short* As = (unsigned short*)smem;            // [2][256*64] = 64 KB
  unsigned short* Bs = (unsigned short*)(smem + 65536);  // [2][256*64] = 64 KB
  unsigned short* tt = (unsigned short*)smem;            // overlay: 4 x [4][64][72] = 144 KB

  const int t = threadIdx.x;
  const int w = t >> 6, lane = t & 63, lr = lane & 15, lg = lane >> 4;
  const int wr = w >> 2, wc = w & 3;  // wave -> 128 rows x 64 cols (one tensor's cols)
  const int hh = w >> 2, dblk = w & 3;  // dots role

  // XCD-chunked swizzle: 256 blocks = 64 mgroups x 4 head-pairs; XCD owns 8 mgroups
  const int id = blockIdx.x;
  const int nid = (id & 7) * 32 + (id >> 3);
  const int mg = nid >> 2, hp = nid & 3;

  const int srl = lane >> 3, sc = lane & 7;

  // staging address precompute: slot i in {0,1}, half H in {0,1}
  int aoff[2][2];
  const unsigned short* bptr[2][2];
#pragma unroll
  for (int i = 0; i < 2; ++i) {
    const int r = (w * 2 + i) * 8 + srl;         // 0..127 within half
    const int swz = (sc ^ (r & 7)) << 3;
#pragma unroll
    for (int H = 0; H < 2; ++H) {
      const int br = H * 128 + r;                // 0..255 B-tile row
      const int grp = br >> 6;                   // 0:K_h 1:V_h 2:K_h2 3:V_h2
      const int grow = ((grp & 1) ? 1024 : 512) +
                       ((grp >> 1) ? (hp + 4) * 64 : hp * 64) + (br & 63);
      bptr[H][i] = wqb + (size_t)grow * 256 + swz;
      aoff[H][i] = (H * 128 + r) * 256 + swz;
    }
  }

  f32x4 acc2[4];
#pragma unroll
  for (int nb = 0; nb < 4; ++nb) acc2[nb] = f32x4{0.f, 0.f, 0.f, 0.f};

  for (int mi = 0; mi < 4; ++mi) {
    const long m0 = ((long)mg * 4 + mi) * 256;
    const unsigned short* am = xb + (size_t)m0 * 256;

    // ---- prologue: stage K-tile 0 into buf0
#pragma unroll
    for (int i = 0; i < 2; ++i) {
      gld_lds16(am + aoff[0][i], &As[(w * 2 + i) * 512]);
      gld_lds16(am + aoff[1][i], &As[8192 + (w * 2 + i) * 512]);
      gld_lds16(bptr[0][i],      &Bs[(w * 2 + i) * 512]);
      gld_lds16(bptr[1][i],      &Bs[8192 + (w * 2 + i) * 512]);
    }
    __syncthreads();

    f32x4 acc[8][4];
#pragma unroll
    for (int i = 0; i < 8; ++i)
#pragma unroll
      for (int j = 0; j < 4; ++j) acc[i][j] = f32x4{0.f, 0.f, 0.f, 0.f};

    bf16x8 a[4][2], b[2][2][2];

    for (int kt = 0; kt < 4; ++kt) {
      const int cur = kt & 1, nxt = cur ^ 1;
      const int kn0 = (kt + 1) * 64;
      const bool st = kt < 3;

      // phase 0: read A(qm0)+B(qn0); stage A-half0; MFMA quad(0,0)
#pragma unroll
      for (int mb = 0; mb < 4; ++mb) {
        const int R = wr * 128 + mb * 16 + lr;
#pragma unroll
        for (int kh = 0; kh < 2; ++kh)
          a[mb][kh] = *(const bf16x8*)&As[cur * 16384 + R * 64 + ((((kh << 2) + lg) ^ (R & 7)) << 3)];
      }
#pragma unroll
      for (int nb = 0; nb < 2; ++nb) {
        const int E = wc * 64 + nb * 16 + lr;
#pragma unroll
        for (int kh = 0; kh < 2; ++kh)
          b[0][nb][kh] = *(const bf16x8*)&Bs[cur * 16384 + E * 64 + ((((kh << 2) + lg) ^ (E & 7)) << 3)];
      }
      if (st) {
#pragma unroll
        for (int i = 0; i < 2; ++i)
          gld_lds16(am + aoff[0][i] + kn0, &As[nxt * 16384 + (w * 2 + i) * 512]);
      }
      __builtin_amdgcn_s_barrier();
      __builtin_amdgcn_s_setprio(1);
#pragma unroll
      for (int mb = 0; mb < 4; ++mb)
#pragma unroll
        for (int nb = 0; nb < 2; ++nb)
#pragma unroll
          for (int kh = 0; kh < 2; ++kh)
            acc[mb][nb] = MFMA16(a[mb][kh], b[0][nb][kh], acc[mb][nb]);
      __builtin_amdgcn_s_setprio(0);
      __builtin_amdgcn_s_barrier();

      // phase 1: read B(qn1); stage A-half1; MFMA quad(0,1)
#pragma unroll
      for (int nb = 0; nb < 2; ++nb) {
        const int E = wc * 64 + 32 + nb * 16 + lr;
#pragma unroll
        for (int kh = 0; kh < 2; ++kh)
          b[1][nb][kh] = *(const bf16x8*)&Bs[cur * 16384 + E * 64 + ((((kh << 2) + lg) ^ (E & 7)) << 3)];
      }
      if (st) {
#pragma unroll
        for (int i = 0; i < 2; ++i)
          gld_lds16(am + aoff[1][i] + kn0, &As[nxt * 16384 + 8192 + (w * 2 + i) * 512]);
      }
      __builtin_amdgcn_s_barrier();
      __builtin_amdgcn_s_setprio(1);
#pragma unroll
      for (int mb = 0; mb < 4; ++mb)
#pragma unroll
        for (int nb = 0; nb < 2; ++nb)
#pragma unroll
          for (int kh = 0; kh < 2; ++kh)
            acc[mb][2 + nb] = MFMA16(a[mb][kh], b[1][nb][kh], acc[mb][2 + nb]);
      __builtin_amdgcn_s_setprio(0);
      __builtin_amdgcn_s_barrier();

      // phase 2: read A(qm1); stage B-half0; MFMA quad(1,0)
#pragma unroll
      for (int mb = 0; mb < 4; ++mb) {
        const int R = wr * 128 + 64 + mb * 16 + lr;
#pragma unroll
        for (int kh = 0; kh < 2; ++kh)
          a[mb][kh] = *(const bf16x8*)&As[cur * 16384 + R * 64 + ((((kh << 2) + lg) ^ (R & 7)) << 3)];
      }
      if (st) {
#pragma unroll
        for (int i = 0; i < 2; ++i)
          gld_lds16(bptr[0][i] + kn0, &Bs[nxt * 16384 + (w * 2 + i) * 512]);
      }
      __builtin_amdgcn_s_barrier();
      __builtin_amdgcn_s_setprio(1);
#pragma unroll
      for (int mb = 0; mb < 4; ++mb)
#pragma unroll
        for (int nb = 0; nb < 2; ++nb)
#pragma unroll
          for (int kh = 0; kh < 2; ++kh)
            acc[4 + mb][nb] = MFMA16(a[mb][kh], b[0][nb][kh], acc[4 + mb][nb]);
      __builtin_amdgcn_s_setprio(0);
      __builtin_amdgcn_s_barrier();

      // phase 3: stage B-half1; MFMA quad(1,1); K-tile boundary drain
      if (st) {
#pragma unroll
        for (int i = 0; i < 2; ++i)
          gld_lds16(bptr[1][i] + kn0, &Bs[nxt * 16384 + 8192 + (w * 2 + i) * 512]);
      }
      __builtin_amdgcn_s_barrier();
      __builtin_amdgcn_s_setprio(1);
#pragma unroll
      for (int mb = 0; mb < 4; ++mb)
#pragma unroll
        for (int nb = 0; nb < 2; ++nb)
#pragma unroll
          for (int kh = 0; kh < 2; ++kh)
            acc[4 + mb][2 + nb] = MFMA16(a[mb][kh], b[1][nb][kh], acc[4 + mb][2 + nb]);
      __builtin_amdgcn_s_setprio(0);
      __syncthreads();
    }

    // ---- instance-norm in-register, write transposed into tt[wc]
    unsigned short* dst = tt + (size_t)wc * 18432;
#pragma unroll
    for (int i = 0; i < 8; ++i) {
      const int cn = wr * 2 + (i >> 2);
      const int mb = i & 3;
#pragma unroll
      for (int rg = 0; rg < 4; ++rg) {
        float s1 = acc[i][0][rg] + acc[i][1][rg] + acc[i][2][rg] + acc[i][3][rg];
        float s2 = acc[i][0][rg] * acc[i][0][rg] + acc[i][1][rg] * acc[i][1][rg] +
                   acc[i][2][rg] * acc[i][2][rg] + acc[i][3][rg] * acc[i][3][rg];
        s1 += __shfl_xor(s1, 1); s2 += __shfl_xor(s2, 1);
        s1 += __shfl_xor(s1, 2); s2 += __shfl_xor(s2, 2);
        s1 += __shfl_xor(s1, 4); s2 += __shfl_xor(s2, 4);
        s1 += __shfl_xor(s1, 8); s2 += __shfl_xor(s2, 8);
        const float mean = s1 * (1.f / 64.f);
        const float rs = rsqrtf(s2 * (1.f / 64.f) - mean * mean + 1e-5f);
        const int nn = mb * 16 + lg * 4 + rg;
#pragma unroll
        for (int nb = 0; nb < 4; ++nb)
          dst[cn * 4608 + (nb * 16 + lr) * 72 + nn] = f2bf((acc[i][nb][rg] - mean) * rs);
      }
    }
    __syncthreads();

    // ---- dots: wave (hh, dblk): D_hh[dblk*16.., e] += sum_n K^T V
    const unsigned short* ktp = tt + (size_t)(hh * 2) * 18432;
    const unsigned short* vtp = tt + (size_t)(hh * 2 + 1) * 18432;
#pragma unroll
    for (int cn = 0; cn < 4; ++cn) {
#pragma unroll
      for (int ns = 0; ns < 64; ns += 32) {
        bf16x8 af = *(const bf16x8*)&ktp[cn * 4608 + (dblk * 16 + lr) * 72 + ns + lg * 8];
#pragma unroll
        for (int nb = 0; nb < 4; ++nb) {
          bf16x8 bv = *(const bf16x8*)&vtp[cn * 4608 + (nb * 16 + lr) * 72 + ns + lg * 8];
          acc2[nb] = MFMA16(af, bv, acc2[nb]);
        }
      }
    }
    __syncthreads();  // tt reads done before next m-tile's staging overwrites
  }

  float* pb = partials + (((size_t)mg * 4 + hp) * 2 + hh) * 4096;
#pragma unroll
  for (int nb = 0; nb < 4; ++nb)
#pragma unroll
    for (int rg = 0; rg < 4; ++rg) {
      const int d = dblk * 16 + lg * 4 + rg;
      const int e = nb * 16 + lr;
      pb[d * 64 + e] = acc2[nb][rg];
    }
}

// ---------------- kernel 4: tmpT[b][k][h*64+e] = (1/N) * sum_d dots_h[d,e] * Wq[h*64+d, k]
// One block per bh; reduces 8 mgroup partials. f32 math, bf16 store.
__global__ __launch_bounds__(256) void k_mmat(const float* __restrict__ partials,
                                              const float* __restrict__ wqkv,
                                              unsigned short* __restrict__ tmpT) {
  __shared__ float dl[4096];        // dots [d][e]
  __shared__ float wqls[64 * 256];  // Wq rows h*64+d: [d][k]
  const int bh = blockIdx.x, b = bh >> 3, h = bh & 7;
  const int t = threadIdx.x;
#pragma unroll
  for (int i = 0; i < 4; ++i) {
    int off = t * 16 + i * 4;
    f32x4 s = {0.f, 0.f, 0.f, 0.f};
    for (int c = 0; c < 8; ++c) {
      const size_t chunk = ((size_t)(b * 8 + c) * 4 + (h & 3)) * 2 + (h >> 2);
      f32x4 p = *(const f32x4*)(partials + chunk * 4096 + off);
      s += p;
    }
    *(f32x4*)&dl[off] = s;
  }
#pragma unroll
  for (int i = 0; i < 16; ++i) {
    int idx4 = i * 256 + t;           // float4 index into [64][256]
    int d = idx4 >> 6, c4 = idx4 & 63;
    *(f32x4*)&wqls[d * 256 + c4 * 4] =
        *(const f32x4*)(wqkv + (size_t)(h * 64 + d) * 256 + c4 * 4);
  }
  __syncthreads();
  const int k = t;
  const float scale = 1.0f / 8192.0f;
  float res[64];
  for (int e = 0; e < 64; ++e) {
    float s = 0.f;
#pragma unroll
    for (int d = 0; d < 64; ++d) s += dl[d * 64 + e] * wqls[d * 256 + k];
    res[e] = s * scale;
  }
  unsigned short* dstp = tmpT + (size_t)b * 131072 + (size_t)k * 512 + h * 64;
#pragma unroll
  for (int e8 = 0; e8 < 8; ++e8) {
    ushort8_t o;
#pragma unroll
    for (int j = 0; j < 8; ++j) o[j] = f2bf(res[e8 * 8 + j]);
    *(ushort8_t*)(dstp + e8 * 8) = o;
  }
}

// ---------------- kernel 5: P^T[b] = woutb(256o x 512he) @ tmpT[b](256k x 512he)
// writes P in gemm2 B-fragment order. Grid 32 = b*4 + (oq*2+kq); 256 thr, 4 waves 2x2.
__global__ __launch_bounds__(256) void k_pmat(const unsigned short* __restrict__ woutb,
                                              const unsigned short* __restrict__ tmpT,
                                              unsigned short* __restrict__ pswz) {
  const int bid = blockIdx.x;
  const int b = bid >> 2, oq = (bid >> 1) & 1, kq = bid & 1;
  const int t = threadIdx.x, w = t >> 6, lane = t & 63, lr = lane & 15, lg = lane >> 4;
  const int wr = w >> 1, wc = w & 1;
  const int ob = oq * 128 + wr * 64, kb = kq * 128 + wc * 64;
  const unsigned short* tb = tmpT + (size_t)b * 131072;

  f32x4 acc[4][4];
#pragma unroll
  for (int mb = 0; mb < 4; ++mb)
#pragma unroll
    for (int nb = 0; nb < 4; ++nb) acc[mb][nb] = f32x4{0.f, 0.f, 0.f, 0.f};

  for (int ks = 0; ks < 16; ++ks) {
    bf16x8 a[4], bb[4];
#pragma unroll
    for (int mb = 0; mb < 4; ++mb)
      a[mb] = *(const bf16x8*)(woutb + (size_t)(ob + mb * 16 + lr) * 512 + ks * 32 + lg * 8);
#pragma unroll
    for (int nb = 0; nb < 4; ++nb)
      bb[nb] = *(const bf16x8*)(tb + (size_t)(kb + nb * 16 + lr) * 512 + ks * 32 + lg * 8);
#pragma unroll
    for (int mb = 0; mb < 4; ++mb)
#pragma unroll
      for (int nb = 0; nb < 4; ++nb) acc[mb][nb] = MFMA16(a[mb], bb[nb], acc[mb][nb]);
  }

  unsigned short* pb = pswz + (size_t)b * 65536;
#pragma unroll
  for (int mb = 0; mb < 4; ++mb)
#pragma unroll
    for (int nb = 0; nb < 4; ++nb)
#pragma unroll
      for (int rg = 0; rg < 4; ++rg) {
        int o = ob + mb * 16 + lg * 4 + rg;
        int k = kb + nb * 16 + lr;
        pb[(((k >> 5) * 16 + (o >> 4)) * 64 + (o & 15) + ((k >> 3) & 3) * 16) * 8 + (k & 7)] =
            f2bf(acc[mb][nb][rg]);
      }
}

// ---------------- kernel 6: out[b] = xb[b] @ P[b] + b_out  (M=8192, N=256, K=256)
__global__ __launch_bounds__(512) void k_gemm2(const unsigned short* __restrict__ xb,
                                               const unsigned short* __restrict__ pswz,
                                               const float* __restrict__ bout,
                                               float* __restrict__ out) {
  __shared__ unsigned short As[2][128 * 64];  // 32 KB
  const int b = blockIdx.x >> 6, mt = blockIdx.x & 63;
  const long m0 = (long)mt * 128;
  const int t = threadIdx.x, w = t >> 6, lane = t & 63, lr = lane & 15, lg = lane >> 4;
  const int wr = w >> 2, wc = w & 3;  // wave: 64 rows x 64 cols
  const unsigned short* qb = xb + ((size_t)b * 8192 + m0) * 256;
  const unsigned short* Mb = pswz + (size_t)b * 65536;
  const int srl = lane >> 3, sc = lane & 7;

#pragma unroll
  for (int i = 0; i < 2; ++i) {
    const int row = (i * 8 + w) * 8 + srl;  // 0..127
    gld_lds16(qb + (size_t)row * 256 + ((sc ^ (row & 7)) << 3),
              &As[0][(i * 8 + w) * 512]);
  }
  __syncthreads();

  f32x4 acc[4][4];
#pragma unroll
  for (int mb = 0; mb < 4; ++mb)
#pragma unroll
    for (int nb = 0; nb < 4; ++nb) acc[mb][nb] = f32x4{0.f, 0.f, 0.f, 0.f};

  for (int ks = 0; ks < 4; ++ks) {
    const int cur = ks & 1, nxt = cur ^ 1;
    if (ks < 3) {
      const int k0 = (ks + 1) * 64;
#pragma unroll
      for (int i = 0; i < 2; ++i) {
        const int row = (i * 8 + w) * 8 + srl;
        gld_lds16(qb + (size_t)row * 256 + k0 + ((sc ^ (row & 7)) << 3),
                  &As[nxt][(i * 8 + w) * 512]);
      }
    }
    bf16x8 a[4][2], bfr[2][4];
#pragma unroll
    for (int mb = 0; mb < 4; ++mb) {
      const int R = wr * 64 + mb * 16 + lr;
#pragma unroll
      for (int kh = 0; kh < 2; ++kh)
        a[mb][kh] = *(const bf16x8*)&As[cur][R * 64 + ((((kh << 2) + lg) ^ (R & 7)) << 3)];
    }
#pragma unroll
    for (int kh = 0; kh < 2; ++kh)
#pragma unroll
      for (int nb = 0; nb < 4; ++nb)
        bfr[kh][nb] = *(const bf16x8*)(Mb + ((((size_t)ks * 2 + kh) * 16 + wc * 4 + nb) * 64 + lane) * 8);
#pragma unroll
    for (int mb = 0; mb < 4; ++mb)
#pragma unroll
      for (int nb = 0; nb < 4; ++nb)
#pragma unroll
        for (int kh = 0; kh < 2; ++kh)
          acc[mb][nb] = MFMA16(a[mb][kh], bfr[kh][nb], acc[mb][nb]);
    __syncthreads();
  }

  float bo[4];
#pragma unroll
  for (int nb = 0; nb < 4; ++nb) bo[nb] = bout[wc * 64 + nb * 16 + lr];
  float* ob = out + ((size_t)b * 8192 + m0) * 256;
#pragma unroll
  for (int mb = 0; mb < 4; ++mb)
#pragma unroll
    for (int nb = 0; nb < 4; ++nb)
#pragma unroll
      for (int rg = 0; rg < 4; ++rg) {
        int row = wr * 64 + mb * 16 + lg * 4 + rg;
        int c = wc * 64 + nb * 16 + lr;
        ob[(size_t)row * 256 + c] = acc[mb][nb][rg] + bo[nb];
      }
}

extern "C" void kernel_launch(void* const* d_in, const int* in_sizes, int n_in,
                              void* d_out, int out_size, void* d_ws, size_t ws_size,
                              hipStream_t stream) {
  const float* x    = (const float*)d_in[0];  // [8,8192,256]
  const float* wqkv = (const float*)d_in[1];  // [1536,256]
  const float* wout = (const float*)d_in[2];  // [256,512]
  const float* bout = (const float*)d_in[3];  // [256]
  float* out = (float*)d_out;                 // [8,8192,256] f32

  char* ws = (char*)d_ws;
  unsigned short* xb = (unsigned short*)ws;                   // 65536*256 bf16 = 32 MB
  size_t off = (size_t)65536 * 256 * 2;
  unsigned short* wqb = (unsigned short*)(ws + off);          // 1536*256 bf16
  off += (size_t)1536 * 256 * 2;
  unsigned short* woutb = (unsigned short*)(ws + off);        // 256*512 bf16
  off += (size_t)256 * 512 * 2;
  float* partials = (float*)(ws + off);                       // 512*4096 f32 = 8 MB
  off += (size_t)512 * 4096 * 4;
  unsigned short* tmpT = (unsigned short*)(ws + off);         // 8*256*512 bf16 = 2 MB
  off += (size_t)8 * 131072 * 2;
  unsigned short* pswz = (unsigned short*)(ws + off);         // 8*256*256 bf16 = 1 MB
  off += (size_t)8 * 65536 * 2;

  k_convx<<<16384, 256, 0, stream>>>(x, xb);
  k_convw<<<384, 256, 0, stream>>>(wqkv, wqb);
  k_convo<<<128, 256, 0, stream>>>(wout, woutb);
  k_fused<<<256, 512, 0, stream>>>(xb, wqb, partials);
  k_mmat<<<64, 256, 0, stream>>>(partials, wqkv, tmpT);
  k_pmat<<<32, 256, 0, stream>>>(woutb, tmpT, pswz);
  k_gemm2<<<512, 512, 0, stream>>>(xb, pswz, bout, out);
}

// Round 8
// 166.045 us; speedup vs baseline: 1.1443x; 1.1443x over previous
//
#include <hip/hip_runtime.h>
#include <hip/hip_bf16.h>
#include <stdint.h>

typedef __attribute__((ext_vector_type(8))) __bf16 bf16x8;
typedef __attribute__((ext_vector_type(8))) unsigned short ushort8_t;
typedef __attribute__((ext_vector_type(4))) unsigned short ushort4_t;
typedef __attribute__((ext_vector_type(4))) float f32x4;

#define MFMA16(a, b, c) __builtin_amdgcn_mfma_f32_16x16x32_bf16((a), (b), (c), 0, 0, 0)

static __device__ __forceinline__ unsigned short f2bf(float f) {
  union { float f; unsigned u; } v; v.f = f;
  unsigned r = v.u + 0x7fffu + ((v.u >> 16) & 1u);  // RNE
  return (unsigned short)(r >> 16);
}
static __device__ __forceinline__ float bf2f(unsigned short u) {
  union { unsigned u; float f; } v; v.u = ((unsigned)u) << 16; return v.f;
}

static __device__ __forceinline__ void gld_lds16(const void* g, void* l) {
  __builtin_amdgcn_global_load_lds((const __attribute__((address_space(1))) void*)g,
                                   (__attribute__((address_space(3))) void*)l, 16, 0, 0);
}

// ---------------- kernel 0a: convert x f32 -> bf16 (row-major [65536][256])
__global__ __launch_bounds__(256) void k_convx(const float* __restrict__ x,
                                               unsigned short* __restrict__ xb) {
  size_t i = ((size_t)blockIdx.x * 256 + threadIdx.x) * 4;  // 16384 blocks exact
  float4 v = *(const float4*)(x + i);
  ushort4_t o = { f2bf(v.x), f2bf(v.y), f2bf(v.z), f2bf(v.w) };
  *(ushort4_t*)(xb + i) = o;
}

// ---------------- kernel 0b: convert w_qkv f32 -> bf16 ([1536][256])
__global__ void k_convw(const float* __restrict__ w, unsigned short* __restrict__ wb) {
  int i = (blockIdx.x * 256 + threadIdx.x) * 4;  // 384 blocks
  float4 v = *(const float4*)(w + i);
  ushort4_t o = { f2bf(v.x), f2bf(v.y), f2bf(v.z), f2bf(v.w) };
  *(ushort4_t*)(wb + i) = o;
}

// ---------------- kernel 0c: convert w_out f32 -> bf16 ([256][512])
__global__ void k_convo(const float* __restrict__ w, unsigned short* __restrict__ wb) {
  int i = (blockIdx.x * 256 + threadIdx.x) * 4;  // 128 blocks
  float4 v = *(const float4*)(w + i);
  ushort4_t o = { f2bf(v.x), f2bf(v.y), f2bf(v.z), f2bf(v.w) };
  *(ushort4_t*)(wb + i) = o;
}

// ---------------- kernel 1: FUSED K/V projection + instance-norm + dots.
// Block = 1 head, 4 m-tiles of 128 rows. 64 KB LDS -> 2 blocks/CU (latency hiding via
// co-resident block). 8 waves of 32rows x 64cols (full d per wave -> in-reg norm).
__global__ __launch_bounds__(512) void k_fused(const unsigned short* __restrict__ xb,
                                               const unsigned short* __restrict__ wqb,
                                               float* __restrict__ partials) {
  __shared__ __align__(16) char smem[65536];
  unsigned short* As = (unsigned short*)smem;            // [2][128*64] = 32 KB
  unsigned short* Bs = (unsigned short*)(smem + 32768);  // [2][128*64] = 32 KB
  unsigned short* kt = (unsigned short*)smem;            // overlay [2][64][72] = 18 KB
  unsigned short* vt = (unsigned short*)(smem + 18432);  // overlay [2][64][72] = 18 KB

  const int t = threadIdx.x;
  const int w = t >> 6, lane = t & 63, lr = lane & 15, lg = lane >> 4;
  const int wr = w >> 1, wc = w & 1;    // GEMM: 32-row strip wr, tensor wc (0=K,1=V)
  const int dblk = w >> 1, ep = w & 1;  // dots role: d-block, e-half

  // XCD-chunked swizzle: 1024 blocks = 128 mgroups x 8 heads; XCD owns 16 mgroups
  const int id = blockIdx.x;
  const int nid = (id & 7) * 128 + (id >> 3);
  const int mg = nid >> 3, h = nid & 7;

  const int srl = lane >> 3, sc = lane & 7;
  const int swz = (sc ^ srl) << 3;      // row%8 == srl for all staging rows

  const unsigned short* bptr[2];
  int aoff[2];
#pragma unroll
  for (int i = 0; i < 2; ++i) {
    const int br = (w * 2 + i) * 8 + srl;   // 0..127
    const int grow = (br < 64) ? (512 + h * 64 + br) : (1024 + h * 64 + (br - 64));
    bptr[i] = wqb + (size_t)grow * 256 + swz;
    aoff[i] = br * 256 + swz;
  }

  f32x4 acc2[2] = {f32x4{0.f, 0.f, 0.f, 0.f}, f32x4{0.f, 0.f, 0.f, 0.f}};

  for (int mi = 0; mi < 4; ++mi) {
    const long m0 = ((long)mg * 4 + mi) * 128;
    const unsigned short* am = xb + (size_t)m0 * 256;

    // prologue: stage K-tile 0 into buf0
#pragma unroll
    for (int i = 0; i < 2; ++i) {
      gld_lds16(am + aoff[i], &As[(w * 2 + i) * 512]);
      gld_lds16(bptr[i],      &Bs[(w * 2 + i) * 512]);
    }
    __syncthreads();

    f32x4 acc[2][4];
#pragma unroll
    for (int mb = 0; mb < 2; ++mb)
#pragma unroll
      for (int nb = 0; nb < 4; ++nb) acc[mb][nb] = f32x4{0.f, 0.f, 0.f, 0.f};

    for (int ktt = 0; ktt < 4; ++ktt) {
      const int cur = ktt & 1, nxt = cur ^ 1;
      if (ktt < 3) {
        const int k0 = (ktt + 1) * 64;
#pragma unroll
        for (int i = 0; i < 2; ++i) {
          gld_lds16(am + aoff[i] + k0, &As[nxt * 8192 + (w * 2 + i) * 512]);
          gld_lds16(bptr[i] + k0,      &Bs[nxt * 8192 + (w * 2 + i) * 512]);
        }
      }
      bf16x8 a[2][2], b[4][2];
#pragma unroll
      for (int mb = 0; mb < 2; ++mb) {
        const int R = wr * 32 + mb * 16 + lr;
#pragma unroll
        for (int kh = 0; kh < 2; ++kh)
          a[mb][kh] = *(const bf16x8*)&As[cur * 8192 + R * 64 + ((((kh << 2) + lg) ^ (R & 7)) << 3)];
      }
#pragma unroll
      for (int nb = 0; nb < 4; ++nb) {
        const int E = wc * 64 + nb * 16 + lr;
#pragma unroll
        for (int kh = 0; kh < 2; ++kh)
          b[nb][kh] = *(const bf16x8*)&Bs[cur * 8192 + E * 64 + ((((kh << 2) + lg) ^ (E & 7)) << 3)];
      }
#pragma unroll
      for (int mb = 0; mb < 2; ++mb)
#pragma unroll
        for (int nb = 0; nb < 4; ++nb)
#pragma unroll
          for (int kh = 0; kh < 2; ++kh)
            acc[mb][nb] = MFMA16(a[mb][kh], b[nb][kh], acc[mb][nb]);
      __syncthreads();
    }

    // ---- instance-norm in-register (full 64 d per wave), transpose into kt/vt overlay
    unsigned short* dst = (wc == 0) ? kt : vt;
#pragma unroll
    for (int mb = 0; mb < 2; ++mb) {
#pragma unroll
      for (int rg = 0; rg < 4; ++rg) {
        float s1 = acc[mb][0][rg] + acc[mb][1][rg] + acc[mb][2][rg] + acc[mb][3][rg];
        float s2 = acc[mb][0][rg] * acc[mb][0][rg] + acc[mb][1][rg] * acc[mb][1][rg] +
                   acc[mb][2][rg] * acc[mb][2][rg] + acc[mb][3][rg] * acc[mb][3][rg];
        s1 += __shfl_xor(s1, 1); s2 += __shfl_xor(s2, 1);
        s1 += __shfl_xor(s1, 2); s2 += __shfl_xor(s2, 2);
        s1 += __shfl_xor(s1, 4); s2 += __shfl_xor(s2, 4);
        s1 += __shfl_xor(s1, 8); s2 += __shfl_xor(s2, 8);
        const float mean = s1 * (1.f / 64.f);
        const float rs = rsqrtf(s2 * (1.f / 64.f) - mean * mean + 1e-5f);
        const int n = wr * 32 + mb * 16 + lg * 4 + rg;
        const int cn = n >> 6, nn = n & 63;
#pragma unroll
        for (int nb = 0; nb < 4; ++nb)
          dst[cn * 4608 + (nb * 16 + lr) * 72 + nn] = f2bf((acc[mb][nb][rg] - mean) * rs);
      }
    }
    __syncthreads();

    // ---- dots: D[d,e] += sum_n K^[n,d] V^[n,e]
#pragma unroll
    for (int cn = 0; cn < 2; ++cn) {
#pragma unroll
      for (int ns = 0; ns < 64; ns += 32) {
        bf16x8 af = *(const bf16x8*)&kt[cn * 4608 + (dblk * 16 + lr) * 72 + ns + lg * 8];
#pragma unroll
        for (int e = 0; e < 2; ++e) {
          bf16x8 bv = *(const bf16x8*)&vt[cn * 4608 + ((ep * 2 + e) * 16 + lr) * 72 + ns + lg * 8];
          acc2[e] = MFMA16(af, bv, acc2[e]);
        }
      }
    }
    __syncthreads();  // overlay reads done before next m-tile staging
  }

  float* pb = partials + ((size_t)mg * 8 + h) * 4096;
#pragma unroll
  for (int e = 0; e < 2; ++e)
#pragma unroll
    for (int rg = 0; rg < 4; ++rg) {
      const int d = dblk * 16 + lg * 4 + rg;
      const int eo = (ep * 2 + e) * 16 + lr;
      pb[d * 64 + eo] = acc2[e][rg];
    }
}

// ---------------- kernel 4: tmpT[b][k][h*64+e] = (1/N) * sum_d dots_h[d,e] * Wq[h*64+d, k]
// One block per bh; reduces 16 mgroup partials. f32 math, bf16 store.
__global__ __launch_bounds__(256) void k_mmat(const float* __restrict__ partials,
                                              const float* __restrict__ wqkv,
                                              unsigned short* __restrict__ tmpT) {
  __shared__ float dl[4096];        // dots [d][e]
  __shared__ float wqls[64 * 256];  // Wq rows h*64+d: [d][k]
  const int bh = blockIdx.x, b = bh >> 3, h = bh & 7;
  const int t = threadIdx.x;
#pragma unroll
  for (int i = 0; i < 4; ++i) {
    int off = t * 16 + i * 4;
    f32x4 s = {0.f, 0.f, 0.f, 0.f};
    for (int c = 0; c < 16; ++c) {
      const size_t chunk = (size_t)(b * 16 + c) * 8 + h;
      f32x4 p = *(const f32x4*)(partials + chunk * 4096 + off);
      s += p;
    }
    *(f32x4*)&dl[off] = s;
  }
#pragma unroll
  for (int i = 0; i < 16; ++i) {
    int idx4 = i * 256 + t;           // float4 index into [64][256]
    int d = idx4 >> 6, c4 = idx4 & 63;
    *(f32x4*)&wqls[d * 256 + c4 * 4] =
        *(const f32x4*)(wqkv + (size_t)(h * 64 + d) * 256 + c4 * 4);
  }
  __syncthreads();
  const int k = t;
  const float scale = 1.0f / 8192.0f;
  float res[64];
  for (int e = 0; e < 64; ++e) {
    float s = 0.f;
#pragma unroll
    for (int d = 0; d < 64; ++d) s += dl[d * 64 + e] * wqls[d * 256 + k];
    res[e] = s * scale;
  }
  unsigned short* dstp = tmpT + (size_t)b * 131072 + (size_t)k * 512 + h * 64;
#pragma unroll
  for (int e8 = 0; e8 < 8; ++e8) {
    ushort8_t o;
#pragma unroll
    for (int j = 0; j < 8; ++j) o[j] = f2bf(res[e8 * 8 + j]);
    *(ushort8_t*)(dstp + e8 * 8) = o;
  }
}

// ---------------- kernel 5: P^T[b] = woutb(256o x 512he) @ tmpT[b](256k x 512he)
// writes P in gemm2 B-fragment order. Grid 32 = b*4 + (oq*2+kq); 256 thr, 4 waves 2x2.
__global__ __launch_bounds__(256) void k_pmat(const unsigned short* __restrict__ woutb,
                                              const unsigned short* __restrict__ tmpT,
                                              unsigned short* __restrict__ pswz) {
  const int bid = blockIdx.x;
  const int b = bid >> 2, oq = (bid >> 1) & 1, kq = bid & 1;
  const int t = threadIdx.x, w = t >> 6, lane = t & 63, lr = lane & 15, lg = lane >> 4;
  const int wr = w >> 1, wc = w & 1;
  const int ob = oq * 128 + wr * 64, kb = kq * 128 + wc * 64;
  const unsigned short* tb = tmpT + (size_t)b * 131072;

  f32x4 acc[4][4];
#pragma unroll
  for (int mb = 0; mb < 4; ++mb)
#pragma unroll
    for (int nb = 0; nb < 4; ++nb) acc[mb][nb] = f32x4{0.f, 0.f, 0.f, 0.f};

  for (int ks = 0; ks < 16; ++ks) {
    bf16x8 a[4], bb[4];
#pragma unroll
    for (int mb = 0; mb < 4; ++mb)
      a[mb] = *(const bf16x8*)(woutb + (size_t)(ob + mb * 16 + lr) * 512 + ks * 32 + lg * 8);
#pragma unroll
    for (int nb = 0; nb < 4; ++nb)
      bb[nb] = *(const bf16x8*)(tb + (size_t)(kb + nb * 16 + lr) * 512 + ks * 32 + lg * 8);
#pragma unroll
    for (int mb = 0; mb < 4; ++mb)
#pragma unroll
      for (int nb = 0; nb < 4; ++nb) acc[mb][nb] = MFMA16(a[mb], bb[nb], acc[mb][nb]);
  }

  unsigned short* pb = pswz + (size_t)b * 65536;
#pragma unroll
  for (int mb = 0; mb < 4; ++mb)
#pragma unroll
    for (int nb = 0; nb < 4; ++nb)
#pragma unroll
      for (int rg = 0; rg < 4; ++rg) {
        int o = ob + mb * 16 + lg * 4 + rg;
        int k = kb + nb * 16 + lr;
        pb[(((k >> 5) * 16 + (o >> 4)) * 64 + (o & 15) + ((k >> 3) & 3) * 16) * 8 + (k & 7)] =
            f2bf(acc[mb][nb][rg]);
      }
}

// ---------------- kernel 6: out[b] = xb[b] @ P[b] + b_out  (M=8192, N=256, K=256)
__global__ __launch_bounds__(512) void k_gemm2(const unsigned short* __restrict__ xb,
                                               const unsigned short* __restrict__ pswz,
                                               const float* __restrict__ bout,
                                               float* __restrict__ out) {
  __shared__ unsigned short As[2][128 * 64];  // 32 KB
  const int b = blockIdx.x >> 6, mt = blockIdx.x & 63;
  const long m0 = (long)mt * 128;
  const int t = threadIdx.x, w = t >> 6, lane = t & 63, lr = lane & 15, lg = lane >> 4;
  const int wr = w >> 2, wc = w & 3;  // wave: 64 rows x 64 cols
  const unsigned short* qb = xb + ((size_t)b * 8192 + m0) * 256;
  const unsigned short* Mb = pswz + (size_t)b * 65536;
  const int srl = lane >> 3, sc = lane & 7;

#pragma unroll
  for (int i = 0; i < 2; ++i) {
    const int row = (i * 8 + w) * 8 + srl;  // 0..127
    gld_lds16(qb + (size_t)row * 256 + ((sc ^ (row & 7)) << 3),
              &As[0][(i * 8 + w) * 512]);
  }
  __syncthreads();

  f32x4 acc[4][4];
#pragma unroll
  for (int mb = 0; mb < 4; ++mb)
#pragma unroll
    for (int nb = 0; nb < 4; ++nb) acc[mb][nb] = f32x4{0.f, 0.f, 0.f, 0.f};

  for (int ks = 0; ks < 4; ++ks) {
    const int cur = ks & 1, nxt = cur ^ 1;
    if (ks < 3) {
      const int k0 = (ks + 1) * 64;
#pragma unroll
      for (int i = 0; i < 2; ++i) {
        const int row = (i * 8 + w) * 8 + srl;
        gld_lds16(qb + (size_t)row * 256 + k0 + ((sc ^ (row & 7)) << 3),
                  &As[nxt][(i * 8 + w) * 512]);
      }
    }
    bf16x8 a[4][2], bfr[2][4];
#pragma unroll
    for (int mb = 0; mb < 4; ++mb) {
      const int R = wr * 64 + mb * 16 + lr;
#pragma unroll
      for (int kh = 0; kh < 2; ++kh)
        a[mb][kh] = *(const bf16x8*)&As[cur][R * 64 + ((((kh << 2) + lg) ^ (R & 7)) << 3)];
    }
#pragma unroll
    for (int kh = 0; kh < 2; ++kh)
#pragma unroll
      for (int nb = 0; nb < 4; ++nb)
        bfr[kh][nb] = *(const bf16x8*)(Mb + ((((size_t)ks * 2 + kh) * 16 + wc * 4 + nb) * 64 + lane) * 8);
#pragma unroll
    for (int mb = 0; mb < 4; ++mb)
#pragma unroll
      for (int nb = 0; nb < 4; ++nb)
#pragma unroll
        for (int kh = 0; kh < 2; ++kh)
          acc[mb][nb] = MFMA16(a[mb][kh], bfr[kh][nb], acc[mb][nb]);
    __syncthreads();
  }

  float bo[4];
#pragma unroll
  for (int nb = 0; nb < 4; ++nb) bo[nb] = bout[wc * 64 + nb * 16 + lr];
  float* ob = out + ((size_t)b * 8192 + m0) * 256;
#pragma unroll
  for (int mb = 0; mb < 4; ++mb)
#pragma unroll
    for (int nb = 0; nb < 4; ++nb)
#pragma unroll
      for (int rg = 0; rg < 4; ++rg) {
        int row = wr * 64 + mb * 16 + lg * 4 + rg;
        int c = wc * 64 + nb * 16 + lr;
        ob[(size_t)row * 256 + c] = acc[mb][nb][rg] + bo[nb];
      }
}

extern "C" void kernel_launch(void* const* d_in, const int* in_sizes, int n_in,
                              void* d_out, int out_size, void* d_ws, size_t ws_size,
                              hipStream_t stream) {
  const float* x    = (const float*)d_in[0];  // [8,8192,256]
  const float* wqkv = (const float*)d_in[1];  // [1536,256]
  const float* wout = (const float*)d_in[2];  // [256,512]
  const float* bout = (const float*)d_in[3];  // [256]
  float* out = (float*)d_out;                 // [8,8192,256] f32

  char* ws = (char*)d_ws;
  unsigned short* xb = (unsigned short*)ws;                   // 65536*256 bf16 = 32 MB
  size_t off = (size_t)65536 * 256 * 2;
  unsigned short* wqb = (unsigned short*)(ws + off);          // 1536*256 bf16
  off += (size_t)1536 * 256 * 2;
  unsigned short* woutb = (unsigned short*)(ws + off);        // 256*512 bf16
  off += (size_t)256 * 512 * 2;
  float* partials = (float*)(ws + off);                       // 1024*4096 f32 = 16 MB
  off += (size_t)1024 * 4096 * 4;
  unsigned short* tmpT = (unsigned short*)(ws + off);         // 8*256*512 bf16 = 2 MB
  off += (size_t)8 * 131072 * 2;
  unsigned short* pswz = (unsigned short*)(ws + off);         // 8*256*256 bf16 = 1 MB
  off += (size_t)8 * 65536 * 2;

  k_convx<<<16384, 256, 0, stream>>>(x, xb);
  k_convw<<<384, 256, 0, stream>>>(wqkv, wqb);
  k_convo<<<128, 256, 0, stream>>>(wout, woutb);
  k_fused<<<1024, 512, 0, stream>>>(xb, wqb, partials);
  k_mmat<<<64, 256, 0, stream>>>(partials, wqkv, tmpT);
  k_pmat<<<32, 256, 0, stream>>>(woutb, tmpT, pswz);
  k_gemm2<<<512, 512, 0, stream>>>(xb, pswz, bout, out);
}